// Round 15
// baseline (288.990 us; speedup 1.0000x reference)
//
#include <hip/hip_runtime.h>
#include <hip/hip_fp16.h>

namespace {

constexpr int CH = 32;
constexpr int HIMG = 192, WIMG = 192, NPIX = HIMG * WIMG;   // 36864
constexpr int WSZ = 16, PADS = 8;
constexpr int NHW = 12, NWIN = 144;
constexpr int MQ = 256, NKEY = 1024;
constexpr int NHEAD = 4, HDIM = 8;
constexpr float SCL = 0.35355339059327373f;   // 8^-0.5

typedef _Float16 half_t;
typedef __attribute__((ext_vector_type(2))) _Float16 h2;
typedef __attribute__((ext_vector_type(2))) float f32x2;

__device__ __forceinline__ h2 mkh2(float v) { half_t h = (half_t)v; h2 r = {h, h}; return r; }

__device__ __forceinline__ f32x2 pkfma(f32x2 a, f32x2 b, f32x2 c) {
  f32x2 d;
  asm("v_pk_fma_f32 %0, %1, %2, %3" : "=v"(d) : "v"(a), "v"(b), "v"(c));
  return d;
}

__device__ __forceinline__ unsigned sortable(float d) {
  unsigned b = __float_as_uint(d);
  if ((b << 1) == 0u) b = 0u;                 // canonicalize -0 -> +0 (pad ties)
  return (b & 0x80000000u) ? ~b : (b | 0x80000000u);
}

// ---------------- proj_sample + xn + fused qn + (block 0) rope trig table ----------------
__global__ __launch_bounds__(256) void k_prep(const float* __restrict__ x,
                                              const float* __restrict__ Ws,
                                              const float* __restrict__ bs,
                                              const float* __restrict__ Wg,
                                              const float* __restrict__ bg,
                                              float* __restrict__ y_px,
                                              float* __restrict__ xn,
                                              float* __restrict__ qn,
                                              float* __restrict__ trigtab) {
  __shared__ float xs[CH][16];
  __shared__ float wg[CH][CH + 1];
  int t = threadIdx.x;
  int pix0 = blockIdx.x * 16;
  for (int i = t; i < CH * 16; i += 256) {
    int c = i >> 4, p = i & 15;
    xs[c][p] = x[c * NPIX + pix0 + p];
  }
  for (int i = t; i < CH * CH; i += 256) wg[i >> 5][i & 31] = Wg[i];
  __syncthreads();
  int o = t & 63, pg = t >> 6;
  {
    float wr[CH];
    const float4* wf = (const float4*)(Ws + o * CH);
#pragma unroll
    for (int r = 0; r < 8; ++r) {
      float4 v = wf[r];
      wr[4 * r] = v.x; wr[4 * r + 1] = v.y; wr[4 * r + 2] = v.z; wr[4 * r + 3] = v.w;
    }
    float bo = bs[o];
#pragma unroll
    for (int pp = 0; pp < 4; ++pp) {
      int p = pg * 4 + pp;
      float a = bo;
#pragma unroll
      for (int c = 0; c < CH; ++c) a += wr[c] * xs[c][p];
      y_px[(pix0 + p) * 64 + o] = a;
    }
  }
  // xn
  if (t < 128) {
    int p = t >> 3, c8 = (t & 7) * 4;
    float v0 = xs[c8][p], v1 = xs[c8 + 1][p], v2 = xs[c8 + 2][p], v3 = xs[c8 + 3][p];
    float ss = v0 * v0 + v1 * v1 + v2 * v2 + v3 * v3;
    ss += __shfl_xor(ss, 1);
    ss += __shfl_xor(ss, 2);
    ss += __shfl_xor(ss, 4);
    float inv = 1.f / fmaxf(sqrtf(ss), 1e-12f);
    float4 outv = make_float4(v0 * inv, v1 * inv, v2 * inv, v3 * inv);
    *(float4*)(xn + (pix0 + p) * CH + c8) = outv;
  }
  // qn
  {
    int ql = t >> 4, i = t & 15;
    float o0 = bg[2 * i], o1 = bg[2 * i + 1];
    const float* w0 = &wg[2 * i][0];
    const float* w1 = &wg[2 * i + 1][0];
#pragma unroll
    for (int c = 0; c < CH; ++c) {
      float xv = xs[c][ql];
      o0 += w0[c] * xv;
      o1 += w1[c] * xv;
    }
    int gy = pix0 / WIMG, gx0 = pix0 % WIMG;
    int win = (gy >> 4) * NHW + (gx0 >> 4);
    int m = (gy & 15) * 16 + ql;
    const float invf[4] = {1.f, 0.1f, 0.01f, 0.001f};
    float ang = (float)m * invf[i & 3];
    float cs = cosf(ang), sn = sinf(ang);
    float r0 = o0 * cs - o1 * sn;
    float r1 = o1 * cs + o0 * sn;
    float ss = r0 * r0 + r1 * r1;
    ss += __shfl_xor(ss, 1);
    ss += __shfl_xor(ss, 2);
    float inv = 1.f / fmaxf(sqrtf(ss), 1e-12f);
    float* qp = qn + ((size_t)(win * MQ + m)) * CH + 2 * i;
    qp[0] = r0 * inv;
    qp[1] = r1 * inv;
  }
  // rope trig table (block 0 only): trig[j][p] = (cos(j*invf[p]), sin(j*invf[p]))
  if (blockIdx.x == 0) {
    const float invf[4] = {1.f, 0.1f, 0.01f, 0.001f};
    for (int j = t; j < NKEY; j += 256) {
      float posj = (float)j;
#pragma unroll
      for (int p = 0; p < 4; ++p) {
        float ang = posj * invf[p];
        float2 cssn = make_float2(cosf(ang), sinf(ang));
        *(float2*)(trigtab + j * 8 + p * 2) = cssn;
      }
    }
  }
}

// ---------------- bilinear downsample 192->96 (antialias triangle) ----------------
__device__ __forceinline__ void down_w(int i, float w[4]) {
  w[0] = 0.125f; w[1] = 0.375f; w[2] = 0.375f; w[3] = 0.125f;
  if (i == 0)  { w[0] = 0.f;            w[1] = 0.75f / 1.75f; w[2] = 0.75f / 1.75f; w[3] = 0.25f / 1.75f; }
  if (i == 95) { w[0] = 0.25f / 1.75f;  w[1] = 0.75f / 1.75f; w[2] = 0.75f / 1.75f; w[3] = 0.f; }
}

__global__ __launch_bounds__(256) void k_down(const float* __restrict__ x,
                                              float* __restrict__ down) {
  int idx = blockIdx.x * 256 + threadIdx.x;
  if (idx >= CH * 96 * 96) return;
  int c = idx / (96 * 96);
  int r = (idx / 96) % 96;
  int q = idx % 96;
  float wr[4], wc[4];
  down_w(r, wr); down_w(q, wc);
  const float* xc = x + c * NPIX;
  float acc = 0.f;
#pragma unroll
  for (int a = 0; a < 4; ++a) {
    int rr = 2 * r - 1 + a;
    rr = rr < 0 ? 0 : (rr > HIMG - 1 ? HIMG - 1 : rr);
    float rowacc = 0.f;
#pragma unroll
    for (int bb = 0; bb < 4; ++bb) {
      int cc = 2 * q - 1 + bb;
      cc = cc < 0 ? 0 : (cc > WIMG - 1 ? WIMG - 1 : cc);
      rowacc += wc[bb] * xc[rr * WIMG + cc];
    }
    acc += wr[a] * rowacc;
  }
  down[idx] = acc;
}

// ---------------- FUSED: upsample-diff + iterative budget alloc; block = window ----------------
__device__ __forceinline__ void up_taps(int i, int& j0, int& j1, float& w0, float& w1) {
  if (i == 0)        { j0 = 0;  j1 = 0;  w0 = 1.f;   w1 = 0.f;   return; }
  if (i == HIMG - 1) { j0 = 95; j1 = 95; w0 = 1.f;   w1 = 0.f;   return; }
  int tt = i >> 1;
  if ((i & 1) == 0)  { j0 = tt - 1; j1 = tt;     w0 = 0.25f; w1 = 0.75f; }
  else               { j0 = tt;     j1 = tt + 1; w0 = 0.75f; w1 = 0.25f; }
}

__global__ __launch_bounds__(256) void k_updalloc(const float* __restrict__ x,
                                                  const float* __restrict__ down,
                                                  int* __restrict__ Kall) {
  __shared__ float red[256];
  int win = blockIdx.x, t = threadIdx.x;
  int wh = win / NHW, ww = win % NHW;
  int hh = wh * WSZ + (t >> 4), wp = ww * WSZ + (t & 15);
  int pix = hh * WIMG + wp;
  int r0, r1, c0, c1; float rw0, rw1, cw0, cw1;
  up_taps(hh, r0, r1, rw0, rw1);
  up_taps(wp, c0, c1, cw0, cw1);
  float var = 0.f;
  for (int c = 0; c < CH; ++c) {
    const float* d = down + c * 96 * 96;
    float up = rw0 * (cw0 * d[r0 * 96 + c0] + cw1 * d[r0 * 96 + c1]) +
               rw1 * (cw0 * d[r1 * 96 + c0] + cw1 * d[r1 * 96 + c1]);
    var += fabsf(x[c * NPIX + pix] - up);
  }
  float rest = 1.f;
  float budget = 65280.f;        // (TOPK-1)*M
  for (int it = 0; it < 4; ++it) {
    float vp = (rest < 1024.f) ? var : 0.f;
    red[t] = vp;
    __syncthreads();
    for (int s = 128; s > 0; s >>= 1) { if (t < s) red[t] += red[t + s]; __syncthreads(); }
    float sum = red[0];
    __syncthreads();
    float prop = vp / fmaxf(sum, 1e-12f);
    float nr = fminf(fmaxf(rest + rintf(prop * budget), 0.f), 1024.f);
    red[t] = nr - rest;
    __syncthreads();
    for (int s = 128; s > 0; s >>= 1) { if (t < s) red[t] += red[t + s]; __syncthreads(); }
    float dsum = red[0];
    __syncthreads();
    budget = fmaxf(budget - dsum, 0.f);
    rest = nr;
  }
  int K = (int)rest + 1;
  Kall[win * MQ + t] = K > 1024 ? 1024 : K;
}

// ---------------- graph: cosine-sim + stable top-K keep mask (R11 structure) ----------------
__global__ __launch_bounds__(512, 4) void k_graph(const float* __restrict__ xn,
                                                  const int* __restrict__ Kall,
                                                  unsigned* __restrict__ graph) {
  constexpr int QPB = 8;
  constexpr int RSTR = 1056;                         // row stride: 1024 vals + 32 pad
  __shared__ __align__(16) unsigned smem[QPB * RSTR];// 33KB: values, then hist alias
  int win = blockIdx.x >> 5;
  int qg  = blockIdx.x & 31;
  int wh = win / NHW, ww = win % NHW;
  int t = threadIdx.x;
  // block-uniform query base pointers (scalar)
  const float4* qb[QPB];
#pragma unroll
  for (int q = 0; q < QPB; ++q) {
    int mq = qg * QPB + q;
    int pixq = (wh * WSZ + (mq >> 4)) * WIMG + ww * WSZ + (mq & 15);
    qb[q] = (const float4*)(xn + pixq * CH);
  }
#pragma unroll 1
  for (int kk = 0; kk < 2; ++kk) {
    int j = kk * 512 + t;
    int k0 = j >> 5, k1 = j & 31;
    int py = wh * WSZ - PADS + k0, px = ww * WSZ - PADS + k1;
    bool inb = (py >= 0) && (py < HIMG) && (px >= 0) && (px < WIMG);
    f32x2 acc2[QPB];
#pragma unroll
    for (int q = 0; q < QPB; ++q) acc2[q] = (f32x2){0.f, 0.f};
    if (inb) {
      const float4* s4 = (const float4*)(xn + (py * WIMG + px) * CH);
#pragma unroll 1
      for (int half = 0; half < 2; ++half) {
        union { float4 v4[4]; f32x2 v2[8]; } Y;
#pragma unroll
        for (int r = 0; r < 4; ++r) Y.v4[r] = s4[half * 4 + r];
#pragma unroll
        for (int c4 = 0; c4 < 4; ++c4) {
          f32x2 y0 = Y.v2[2 * c4], y1 = Y.v2[2 * c4 + 1];
#pragma unroll
          for (int q = 0; q < QPB; ++q) {
            float4 qv = qb[q][half * 4 + c4];        // uniform -> s_load
            f32x2 qa = {qv.x, qv.y}, qb2 = {qv.z, qv.w};
            acc2[q] = pkfma(qa, y0, acc2[q]);
            acc2[q] = pkfma(qb2, y1, acc2[q]);
          }
        }
      }
    }
#pragma unroll
    for (int q = 0; q < QPB; ++q) smem[q * RSTR + j] = sortable(acc2[q].x + acc2[q].y);
  }
  __syncthreads();
  // ---- select: wave w owns query m = qg*QPB + w; row w is wave-exclusive ----
  int w = t >> 6, l = t & 63;
  unsigned* row = &smem[w * RSTR];
  int m = qg * QPB + w;
  int K = Kall[win * MQ + m];
  unsigned row32 = (unsigned)(win * MQ + m) * 32u;
  if (K >= NKEY) {                       // keep everything
    if (l < 32) graph[row32 + l] = ~0u;
    return;
  }
  unsigned v[16];
#pragma unroll
  for (int k = 0; k < 16; ++k) v[k] = row[k * 64 + l];
  __asm__ volatile("s_waitcnt lgkmcnt(0)" ::: "memory");  // row reads done before overwrite
  unsigned pref = 0;
  int remK = K;
  int shift = 24;
  unsigned ustar = 0;
  int quota = 0;
  for (int pass = 0; pass < 4; ++pass) {
    uint4 z = make_uint4(0u, 0u, 0u, 0u);
    if (pass == 0) {                     // zero 4 skewed copies (words 0..1055)
#pragma unroll
      for (int c = 0; c < 4; ++c) *(uint4*)&row[c * 256 + l * 4] = z;
      if (l < 8) *(uint4*)&row[1024 + l * 4] = z;
    } else {
      *(uint4*)&row[l * 4] = z;
    }
    __asm__ volatile("s_waitcnt lgkmcnt(0)" ::: "memory");
    int cbase = (l & 3) * 257;           // bank-skewed copy for this lane
#pragma unroll
    for (int k = 0; k < 16; ++k) {
      unsigned u = v[k];
      bool ok = (pass == 0) || ((u >> ((shift + 8) & 31)) == pref);
      if (ok) {
        unsigned bin = (u >> shift) & 255u;
        atomicAdd(&row[(pass == 0 ? cbase : 0) + bin], 1u);
      }
    }
    __asm__ volatile("s_waitcnt lgkmcnt(0)" ::: "memory");
    unsigned c0, c1, c2, c3;
    if (pass == 0) {
      c0 = c1 = c2 = c3 = 0u;
#pragma unroll
      for (int c = 0; c < 4; ++c) {
        c0 += row[c * 257 + l * 4 + 0];
        c1 += row[c * 257 + l * 4 + 1];
        c2 += row[c * 257 + l * 4 + 2];
        c3 += row[c * 257 + l * 4 + 3];
      }
    } else {
      uint4 hv = *(const uint4*)&row[l * 4];
      c0 = hv.x; c1 = hv.y; c2 = hv.z; c3 = hv.w;
    }
    unsigned s3 = c3, s2 = c3 + c2, s1 = s2 + c1, s0 = s1 + c0;
    unsigned I = s0;
#pragma unroll
    for (int off = 1; off < 64; off <<= 1) {
      unsigned tv = __shfl_down(I, off);
      if (l + off < 64) I += tv;
    }
    unsigned E = I - s0;   // counts in lanes above (higher bins)
    int bin = -1, newrem = 0;
    bool early = false;
    {
      int sb, sb1;
      sb = (int)(s3 + E); sb1 = (int)E;
      if (sb >= remK && sb1 < remK) { bin = l * 4 + 3; newrem = remK - sb1; early = (sb == remK); }
      sb = (int)(s2 + E); sb1 = (int)(s3 + E);
      if (sb >= remK && sb1 < remK) { bin = l * 4 + 2; newrem = remK - sb1; early = (sb == remK); }
      sb = (int)(s1 + E); sb1 = (int)(s2 + E);
      if (sb >= remK && sb1 < remK) { bin = l * 4 + 1; newrem = remK - sb1; early = (sb == remK); }
      sb = (int)(s0 + E); sb1 = (int)(s1 + E);
      if (sb >= remK && sb1 < remK) { bin = l * 4 + 0; newrem = remK - sb1; early = (sb == remK); }
    }
    unsigned long long bal = __ballot(bin >= 0);
    int src = __ffsll((long long)bal) - 1;
    int pk = newrem | (bin << 11) | (early ? (1 << 20) : 0);
    pk = __shfl(pk, src);
    pref = (pref << 8) | (unsigned)((pk >> 11) & 255);
    remK = pk & 0x7FF;
    if (((pk >> 20) & 1) || pass == 3) { ustar = pref << shift; quota = remK; break; }
    // exact-resolve: if all candidates matching the new prefix are equal, done
    unsigned mn = ~0u, mx = 0u;
#pragma unroll
    for (int k = 0; k < 16; ++k) {
      if ((v[k] >> shift) == pref) {
        mn = v[k] < mn ? v[k] : mn;
        mx = v[k] > mx ? v[k] : mx;
      }
    }
#pragma unroll
    for (int off = 1; off < 64; off <<= 1) {
      unsigned mno = (unsigned)__shfl_xor((int)mn, off);
      unsigned mxo = (unsigned)__shfl_xor((int)mx, off);
      mn = mno < mn ? mno : mn;
      mx = mxo > mx ? mxo : mx;
    }
    if (mn == mx) { ustar = mn; quota = remK; break; }
    shift -= 8;
  }
  // ---- keep mask: stable (ascending key index) among ties; coalesced write ----
  int running = 0;
  unsigned saved = 0;
#pragma unroll
  for (int k = 0; k < 16; ++k) {
    unsigned u = v[k];
    bool eq = (u == ustar);
    unsigned long long beq = __ballot(eq);
    int before = running + (int)__popcll(beq & ((1ull << l) - 1ull));
    bool keep = (u > ustar) || (eq && before < quota);
    running += (int)__popcll(beq);
    unsigned long long kb = __ballot(keep);
    if ((l >> 1) == k) saved = (l & 1) ? (unsigned)(kb >> 32) : (unsigned)kb;
  }
  if (l < 32) graph[row32 + l] = saved;
}

// ---------------- attention: ONE 1024-thread block per (win, head); staging deduped 4x ----------------
#define MERGEA(MSK) {                                              \
  float mo = __shfl_xor(mrun, MSK);                                \
  float lo = __shfl_xor(lrun, MSK);                                \
  float b0 = __shfl_xor(__builtin_bit_cast(float, a0), MSK);       \
  float b1 = __shfl_xor(__builtin_bit_cast(float, a1), MSK);       \
  float b2 = __shfl_xor(__builtin_bit_cast(float, a2), MSK);       \
  float b3 = __shfl_xor(__builtin_bit_cast(float, a3), MSK);       \
  float mn = fmaxf(mrun, mo);                                      \
  float c1 = __expf(mrun - mn), c2 = __expf(mo - mn);              \
  lrun = lrun * c1 + lo * c2;                                      \
  h2 c1h = mkh2(c1), c2h = mkh2(c2);                               \
  a0 = a0 * c1h + __builtin_bit_cast(h2, b0) * c2h;                \
  a1 = a1 * c1h + __builtin_bit_cast(h2, b1) * c2h;                \
  a2 = a2 * c1h + __builtin_bit_cast(h2, b2) * c2h;                \
  a3 = a3 * c1h + __builtin_bit_cast(h2, b3) * c2h;                \
  mrun = mn; }

__global__ __launch_bounds__(1024) void k_attn(const float* __restrict__ qn,
                                               const float* __restrict__ y_px,
                                               const float* __restrict__ trigtab,
                                               const unsigned* __restrict__ graph,
                                               float* __restrict__ att) {
  __shared__ uint4 knp[NKEY];   // 16KB: 8 x fp16 normalized rope'd k
  __shared__ uint4 fvp[NKEY];   // 16KB: 8 x fp16 v
  int bid = blockIdx.x;
  int h   = bid & 3;
  int win = bid >> 2;
  int wh = win / NHW, ww = win % NHW;
  int t = threadIdx.x;
  const float4* tg = (const float4*)trigtab;
  {
    int j = t;
    int k0 = j >> 5, k1 = j & 31;
    int py = wh * WSZ - PADS + k0, px = ww * WSZ - PADS + k1;
    bool inb = (py >= 0) && (py < HIMG) && (px >= 0) && (px < WIMG);
    float kv[8], fw[8];
    if (inb) {
      const float* src = y_px + (py * WIMG + px) * 64 + h * HDIM;
      const float4* a4 = (const float4*)src;
      const float4* b4 = (const float4*)(src + 32);
      float4 a0 = a4[0], a1 = a4[1], b0 = b4[0], b1 = b4[1];
      kv[0]=a0.x; kv[1]=a0.y; kv[2]=a0.z; kv[3]=a0.w;
      kv[4]=a1.x; kv[5]=a1.y; kv[6]=a1.z; kv[7]=a1.w;
      fw[0]=b0.x; fw[1]=b0.y; fw[2]=b0.z; fw[3]=b0.w;
      fw[4]=b1.x; fw[5]=b1.y; fw[6]=b1.z; fw[7]=b1.w;
    } else {
#pragma unroll
      for (int d = 0; d < 8; ++d) { kv[d] = 0.f; fw[d] = 0.f; }
    }
    float4 T0 = tg[j * 2], T1 = tg[j * 2 + 1];   // (c0,s0,c1,s1), (c2,s2,c3,s3)
    float ro[8];
    ro[0] = kv[0] * T0.x - kv[1] * T0.y;
    ro[1] = kv[1] * T0.x + kv[0] * T0.y;
    ro[2] = kv[2] * T0.z - kv[3] * T0.w;
    ro[3] = kv[3] * T0.z + kv[2] * T0.w;
    ro[4] = kv[4] * T1.x - kv[5] * T1.y;
    ro[5] = kv[5] * T1.x + kv[4] * T1.y;
    ro[6] = kv[6] * T1.z - kv[7] * T1.w;
    ro[7] = kv[7] * T1.z + kv[6] * T1.w;
    float ss = 0.f;
#pragma unroll
    for (int d = 0; d < 8; ++d) ss += ro[d] * ro[d];
    float iv = 1.f / fmaxf(sqrtf(ss), 1e-12f);
    union { uint4 u; h2 v[4]; } ku, fu;
#pragma unroll
    for (int p = 0; p < 4; ++p) {
      h2 kk = { (half_t)(ro[2*p] * iv), (half_t)(ro[2*p+1] * iv) };
      h2 ff = { (half_t)fw[2*p], (half_t)fw[2*p+1] };
      ku.v[p] = kk; fu.v[p] = ff;
    }
    knp[j] = ku.u;
    fvp[j] = fu.u;
  }
  __syncthreads();
  int s = t & 3, m = t >> 2;
  const float* qp = qn + (win * MQ + m) * CH + h * HDIM;
  h2 q0 = { (half_t)qp[0], (half_t)qp[1] };
  h2 q1 = { (half_t)qp[2], (half_t)qp[3] };
  h2 q2 = { (half_t)qp[4], (half_t)qp[5] };
  h2 q3 = { (half_t)qp[6], (half_t)qp[7] };
  const unsigned* gr = graph + (size_t)(win * MQ + m) * 32 + s * 8;
  float mrun = -1e30f, lrun = 0.f;
  h2 a0 = {0,0}, a1 = {0,0}, a2 = {0,0}, a3 = {0,0};
  int jbase = s * 256;
  for (int w8 = 0; w8 < 8; ++w8) {
    unsigned bits = gr[w8];
    while (bits) {
      int bb = __ffs(bits) - 1;
      bits &= bits - 1;
      int j = jbase + w8 * 32 + bb;
      uint4 kv = knp[j];
      float sd = __builtin_amdgcn_fdot2(q0, __builtin_bit_cast(h2, kv.x), 0.f, false);
      sd = __builtin_amdgcn_fdot2(q1, __builtin_bit_cast(h2, kv.y), sd, false);
      sd = __builtin_amdgcn_fdot2(q2, __builtin_bit_cast(h2, kv.z), sd, false);
      sd = __builtin_amdgcn_fdot2(q3, __builtin_bit_cast(h2, kv.w), sd, false);
      sd *= SCL;
      uint4 fw = fvp[j];
      if (sd <= mrun) {
        float pw = __expf(sd - mrun);
        lrun += pw;
        h2 ph = mkh2(pw);
        a0 += __builtin_bit_cast(h2, fw.x) * ph;
        a1 += __builtin_bit_cast(h2, fw.y) * ph;
        a2 += __builtin_bit_cast(h2, fw.z) * ph;
        a3 += __builtin_bit_cast(h2, fw.w) * ph;
      } else {
        float corr = __expf(mrun - sd);
        lrun = lrun * corr + 1.f;
        h2 ch = mkh2(corr);
        a0 = a0 * ch + __builtin_bit_cast(h2, fw.x);
        a1 = a1 * ch + __builtin_bit_cast(h2, fw.y);
        a2 = a2 * ch + __builtin_bit_cast(h2, fw.z);
        a3 = a3 * ch + __builtin_bit_cast(h2, fw.w);
        mrun = sd;
      }
    }
  }
  MERGEA(1);
  MERGEA(2);
  float invl = 1.f / lrun;
  h2 sel;
  if (s == 0) sel = a0; else if (s == 1) sel = a1; else if (s == 2) sel = a2; else sel = a3;
  float* op = att + (size_t)(win * MQ + m) * CH + h * HDIM + s * 2;
  op[0] = (float)sel.x * invl;
  op[1] = (float)sel.y * invl;
}

// ---------------- out @ Wp^T + bp -> image layout; 64 px x 4 oc-quarters ----------------
__global__ __launch_bounds__(256) void k_img(const float* __restrict__ att,
                                             const float* __restrict__ Wp,
                                             const float* __restrict__ bp,
                                             float* __restrict__ img) {
  __shared__ __align__(16) float w[CH * CH];
  __shared__ float b[CH];
  int t = threadIdx.x;
  for (int i = t; i < CH * CH; i += 256) w[i] = Wp[i];
  if (t < CH) b[t] = bp[t];
  __syncthreads();
  int g = t >> 6, lane = t & 63;
  int gq = blockIdx.x * 64 + lane;
  int win = gq >> 8, m = gq & 255;
  int wh = win / NHW, ww = win % NHW;
  int pix = (wh * WSZ + (m >> 4)) * WIMG + ww * WSZ + (m & 15);
  union { float4 v4[8]; float f[CH]; } a;
  const float4* ap = (const float4*)(att + (size_t)gq * CH);
#pragma unroll
  for (int r = 0; r < 8; ++r) a.v4[r] = ap[r];
#pragma unroll
  for (int k = 0; k < 8; ++k) {
    int oc = g * 8 + k;
    float acc = b[oc];
    const float4* wv = (const float4*)&w[oc * CH];
#pragma unroll
    for (int c4 = 0; c4 < 8; ++c4) {
      float4 wq = wv[c4];
      acc += wq.x * a.f[4*c4] + wq.y * a.f[4*c4+1] + wq.z * a.f[4*c4+2] + wq.w * a.f[4*c4+3];
    }
    img[oc * NPIX + pix] = acc;
  }
}

// ---------------- 3x3 conv + channel LayerNorm + residual ----------------
#define CACC(W, I0) { o[I0] += (W).x * xv; o[I0+1] += (W).y * xv; o[I0+2] += (W).z * xv; o[I0+3] += (W).w * xv; }

__global__ __launch_bounds__(256) void k_convln(const float* __restrict__ img,
                                                const float* __restrict__ Wc,
                                                const float* __restrict__ bc,
                                                const float* __restrict__ gamma,
                                                const float* __restrict__ beta,
                                                float* __restrict__ out) {
  __shared__ float tile[CH][10][18];              // 23.0 KB
  __shared__ __align__(16) float wt[288][CH];     // 36.9 KB, transposed weights
  __shared__ float red[128][2][2];                // 2 KB
  int t = threadIdx.x;
  int by = (blockIdx.x / 12) * 8, bx = (blockIdx.x % 12) * 16;
  for (int i = t; i < 288 * CH; i += 256) {
    int oc = i & 31, icd = i >> 5;
    wt[icd][oc] = Wc[oc * 288 + icd];
  }
  for (int i = t; i < CH * 10 * 18; i += 256) {
    int c = i / 180; int rr = (i % 180) / 18; int cl = i % 18;
    int gy = by + rr - 1, gx = bx + cl - 1;
    tile[c][rr][cl] = (gy >= 0 && gy < HIMG && gx >= 0 && gx < WIMG)
                          ? img[c * NPIX + gy * WIMG + gx] : 0.f;
  }
  __syncthreads();
  int g = __builtin_amdgcn_readfirstlane((t >> 7) & 1);   // wave-uniform oc half
  int p = t & 127;
  int r = p >> 4, c = p & 15;
  int ocb = g * 16;
  float o[16];
#pragma unroll
  for (int k = 0; k < 16; ++k) o[k] = bc[ocb + k];
  for (int ic = 0; ic < CH; ++ic) {
#pragma unroll
    for (int dy = 0; dy < 3; ++dy) {
#pragma unroll
      for (int dx = 0; dx < 3; ++dx) {
        float xv = tile[ic][r + dy][c + dx];
        const float4* wv = (const float4*)&wt[ic * 9 + dy * 3 + dx][ocb];
        float4 w0 = wv[0], w1 = wv[1], w2 = wv[2], w3 = wv[3];
        CACC(w0, 0); CACC(w1, 4); CACC(w2, 8); CACC(w3, 12);
      }
    }
  }
  float s1 = 0.f, s2 = 0.f;
#pragma unroll
  for (int k = 0; k < 16; ++k) { s1 += o[k]; s2 += o[k] * o[k]; }
  red[p][g][0] = s1; red[p][g][1] = s2;
  __syncthreads();
  float t1 = red[p][g ^ 1][0], t2 = red[p][g ^ 1][1];
  float mu = (s1 + t1) * (1.f / 32.f);
  float ex2 = (s2 + t2) * (1.f / 32.f);
  float var = ex2 - mu * mu;
  float inv = 1.f / sqrtf(var + 1e-5f);
  int pix = (by + r) * WIMG + bx + c;
#pragma unroll
  for (int k = 0; k < 16; ++k) {
    int oc = ocb + k;
    out[oc * NPIX + pix] = tile[oc][r + 1][c + 1] + (o[k] - mu) * inv * gamma[oc] + beta[oc];
  }
}

}  // namespace

extern "C" void kernel_launch(void* const* d_in, const int* in_sizes, int n_in,
                              void* d_out, int out_size, void* d_ws, size_t ws_size,
                              hipStream_t stream) {
  const float* x     = (const float*)d_in[0];
  const float* Wg    = (const float*)d_in[1];
  const float* bg    = (const float*)d_in[2];
  const float* Ws    = (const float*)d_in[3];
  const float* bs    = (const float*)d_in[4];
  const float* Wp    = (const float*)d_in[5];
  const float* bp    = (const float*)d_in[6];
  const float* Wc    = (const float*)d_in[7];
  const float* bc    = (const float*)d_in[8];
  const float* gamma = (const float*)d_in[9];
  const float* beta  = (const float*)d_in[10];
  float* out = (float*)d_out;
  float* ws = (float*)d_ws;

  float* y_px = ws;                             // 2359296 floats
  float* xn   = y_px + 2359296;                 // 1179648
  float* down = xn + 1179648;                   // 294912
  float* trigtab = down + 294912;               // 8192 used (old Xd slot, 36864)
  float* qn   = trigtab + 36864;                // 1179648
  float* att  = qn + 1179648;                   // 1179648
  float* img  = att + 1179648;                  // 1179648
  int* Kall   = (int*)(img + 1179648);          // 36864
  unsigned* graph = (unsigned*)(Kall + 36864);  // 1179648
  if (ws_size < (size_t)8626176 * 4) return;

  k_prep<<<NPIX / 16, 256, 0, stream>>>(x, Ws, bs, Wg, bg, y_px, xn, qn, trigtab);
  k_down<<<(CH * 96 * 96) / 256, 256, 0, stream>>>(x, down);
  k_updalloc<<<NWIN, 256, 0, stream>>>(x, down, Kall);
  k_graph<<<NWIN * 32, 512, 0, stream>>>(xn, Kall, graph);
  k_attn<<<NWIN * NHEAD, 1024, 0, stream>>>(qn, y_px, trigtab, graph, att);
  k_img<<<NPIX / 64, 256, 0, stream>>>(att, Wp, bp, img);
  k_convln<<<288, 256, 0, stream>>>(img, Wc, bc, gamma, beta, out);
}

// Round 16
// 284.312 us; speedup vs baseline: 1.0165x; 1.0165x over previous
//
#include <hip/hip_runtime.h>
#include <hip/hip_fp16.h>

namespace {

constexpr int CH = 32;
constexpr int HIMG = 192, WIMG = 192, NPIX = HIMG * WIMG;   // 36864
constexpr int WSZ = 16, PADS = 8;
constexpr int NHW = 12, NWIN = 144;
constexpr int MQ = 256, NKEY = 1024;
constexpr int NHEAD = 4, HDIM = 8;
constexpr float SCL = 0.35355339059327373f;   // 8^-0.5

typedef _Float16 half_t;
typedef __attribute__((ext_vector_type(2))) _Float16 h2;
typedef __attribute__((ext_vector_type(2))) float f32x2;

__device__ __forceinline__ h2 mkh2(float v) { half_t h = (half_t)v; h2 r = {h, h}; return r; }

__device__ __forceinline__ f32x2 pkfma(f32x2 a, f32x2 b, f32x2 c) {
  f32x2 d;
  asm("v_pk_fma_f32 %0, %1, %2, %3" : "=v"(d) : "v"(a), "v"(b), "v"(c));
  return d;
}

__device__ __forceinline__ unsigned sortable(float d) {
  unsigned b = __float_as_uint(d);
  if ((b << 1) == 0u) b = 0u;                 // canonicalize -0 -> +0 (pad ties)
  return (b & 0x80000000u) ? ~b : (b | 0x80000000u);
}

// ---------------- proj_sample + xn + fused qn + (block 0) rope trig table ----------------
__global__ __launch_bounds__(256) void k_prep(const float* __restrict__ x,
                                              const float* __restrict__ Ws,
                                              const float* __restrict__ bs,
                                              const float* __restrict__ Wg,
                                              const float* __restrict__ bg,
                                              float* __restrict__ y_px,
                                              float* __restrict__ xn,
                                              float* __restrict__ qn,
                                              float* __restrict__ trigtab) {
  __shared__ float xs[CH][16];
  __shared__ float wg[CH][CH + 1];
  int t = threadIdx.x;
  int pix0 = blockIdx.x * 16;
  for (int i = t; i < CH * 16; i += 256) {
    int c = i >> 4, p = i & 15;
    xs[c][p] = x[c * NPIX + pix0 + p];
  }
  for (int i = t; i < CH * CH; i += 256) wg[i >> 5][i & 31] = Wg[i];
  __syncthreads();
  int o = t & 63, pg = t >> 6;
  {
    float wr[CH];
    const float4* wf = (const float4*)(Ws + o * CH);
#pragma unroll
    for (int r = 0; r < 8; ++r) {
      float4 v = wf[r];
      wr[4 * r] = v.x; wr[4 * r + 1] = v.y; wr[4 * r + 2] = v.z; wr[4 * r + 3] = v.w;
    }
    float bo = bs[o];
#pragma unroll
    for (int pp = 0; pp < 4; ++pp) {
      int p = pg * 4 + pp;
      float a = bo;
#pragma unroll
      for (int c = 0; c < CH; ++c) a += wr[c] * xs[c][p];
      y_px[(pix0 + p) * 64 + o] = a;
    }
  }
  // xn
  if (t < 128) {
    int p = t >> 3, c8 = (t & 7) * 4;
    float v0 = xs[c8][p], v1 = xs[c8 + 1][p], v2 = xs[c8 + 2][p], v3 = xs[c8 + 3][p];
    float ss = v0 * v0 + v1 * v1 + v2 * v2 + v3 * v3;
    ss += __shfl_xor(ss, 1);
    ss += __shfl_xor(ss, 2);
    ss += __shfl_xor(ss, 4);
    float inv = 1.f / fmaxf(sqrtf(ss), 1e-12f);
    float4 outv = make_float4(v0 * inv, v1 * inv, v2 * inv, v3 * inv);
    *(float4*)(xn + (pix0 + p) * CH + c8) = outv;
  }
  // qn
  {
    int ql = t >> 4, i = t & 15;
    float o0 = bg[2 * i], o1 = bg[2 * i + 1];
    const float* w0 = &wg[2 * i][0];
    const float* w1 = &wg[2 * i + 1][0];
#pragma unroll
    for (int c = 0; c < CH; ++c) {
      float xv = xs[c][ql];
      o0 += w0[c] * xv;
      o1 += w1[c] * xv;
    }
    int gy = pix0 / WIMG, gx0 = pix0 % WIMG;
    int win = (gy >> 4) * NHW + (gx0 >> 4);
    int m = (gy & 15) * 16 + ql;
    const float invf[4] = {1.f, 0.1f, 0.01f, 0.001f};
    float ang = (float)m * invf[i & 3];
    float cs = cosf(ang), sn = sinf(ang);
    float r0 = o0 * cs - o1 * sn;
    float r1 = o1 * cs + o0 * sn;
    float ss = r0 * r0 + r1 * r1;
    ss += __shfl_xor(ss, 1);
    ss += __shfl_xor(ss, 2);
    float inv = 1.f / fmaxf(sqrtf(ss), 1e-12f);
    float* qp = qn + ((size_t)(win * MQ + m)) * CH + 2 * i;
    qp[0] = r0 * inv;
    qp[1] = r1 * inv;
  }
  // rope trig table (block 0 only): trig[j][p] = (cos(j*invf[p]), sin(j*invf[p]))
  if (blockIdx.x == 0) {
    const float invf[4] = {1.f, 0.1f, 0.01f, 0.001f};
    for (int j = t; j < NKEY; j += 256) {
      float posj = (float)j;
#pragma unroll
      for (int p = 0; p < 4; ++p) {
        float ang = posj * invf[p];
        float2 cssn = make_float2(cosf(ang), sinf(ang));
        *(float2*)(trigtab + j * 8 + p * 2) = cssn;
      }
    }
  }
}

// ---------------- bilinear downsample 192->96 (antialias triangle) ----------------
__device__ __forceinline__ void down_w(int i, float w[4]) {
  w[0] = 0.125f; w[1] = 0.375f; w[2] = 0.375f; w[3] = 0.125f;
  if (i == 0)  { w[0] = 0.f;            w[1] = 0.75f / 1.75f; w[2] = 0.75f / 1.75f; w[3] = 0.25f / 1.75f; }
  if (i == 95) { w[0] = 0.25f / 1.75f;  w[1] = 0.75f / 1.75f; w[2] = 0.75f / 1.75f; w[3] = 0.f; }
}

__global__ __launch_bounds__(256) void k_down(const float* __restrict__ x,
                                              float* __restrict__ down) {
  int idx = blockIdx.x * 256 + threadIdx.x;
  if (idx >= CH * 96 * 96) return;
  int c = idx / (96 * 96);
  int r = (idx / 96) % 96;
  int q = idx % 96;
  float wr[4], wc[4];
  down_w(r, wr); down_w(q, wc);
  const float* xc = x + c * NPIX;
  float acc = 0.f;
#pragma unroll
  for (int a = 0; a < 4; ++a) {
    int rr = 2 * r - 1 + a;
    rr = rr < 0 ? 0 : (rr > HIMG - 1 ? HIMG - 1 : rr);
    float rowacc = 0.f;
#pragma unroll
    for (int bb = 0; bb < 4; ++bb) {
      int cc = 2 * q - 1 + bb;
      cc = cc < 0 ? 0 : (cc > WIMG - 1 ? WIMG - 1 : cc);
      rowacc += wc[bb] * xc[rr * WIMG + cc];
    }
    acc += wr[a] * rowacc;
  }
  down[idx] = acc;
}

// ---------------- FUSED: upsample-diff + iterative budget alloc; block = window ----------------
__device__ __forceinline__ void up_taps(int i, int& j0, int& j1, float& w0, float& w1) {
  if (i == 0)        { j0 = 0;  j1 = 0;  w0 = 1.f;   w1 = 0.f;   return; }
  if (i == HIMG - 1) { j0 = 95; j1 = 95; w0 = 1.f;   w1 = 0.f;   return; }
  int tt = i >> 1;
  if ((i & 1) == 0)  { j0 = tt - 1; j1 = tt;     w0 = 0.25f; w1 = 0.75f; }
  else               { j0 = tt;     j1 = tt + 1; w0 = 0.75f; w1 = 0.25f; }
}

__global__ __launch_bounds__(256) void k_updalloc(const float* __restrict__ x,
                                                  const float* __restrict__ down,
                                                  int* __restrict__ Kall) {
  __shared__ float red[256];
  int win = blockIdx.x, t = threadIdx.x;
  int wh = win / NHW, ww = win % NHW;
  int hh = wh * WSZ + (t >> 4), wp = ww * WSZ + (t & 15);
  int pix = hh * WIMG + wp;
  int r0, r1, c0, c1; float rw0, rw1, cw0, cw1;
  up_taps(hh, r0, r1, rw0, rw1);
  up_taps(wp, c0, c1, cw0, cw1);
  float var = 0.f;
  for (int c = 0; c < CH; ++c) {
    const float* d = down + c * 96 * 96;
    float up = rw0 * (cw0 * d[r0 * 96 + c0] + cw1 * d[r0 * 96 + c1]) +
               rw1 * (cw0 * d[r1 * 96 + c0] + cw1 * d[r1 * 96 + c1]);
    var += fabsf(x[c * NPIX + pix] - up);
  }
  float rest = 1.f;
  float budget = 65280.f;        // (TOPK-1)*M
  for (int it = 0; it < 4; ++it) {
    float vp = (rest < 1024.f) ? var : 0.f;
    red[t] = vp;
    __syncthreads();
    for (int s = 128; s > 0; s >>= 1) { if (t < s) red[t] += red[t + s]; __syncthreads(); }
    float sum = red[0];
    __syncthreads();
    float prop = vp / fmaxf(sum, 1e-12f);
    float nr = fminf(fmaxf(rest + rintf(prop * budget), 0.f), 1024.f);
    red[t] = nr - rest;
    __syncthreads();
    for (int s = 128; s > 0; s >>= 1) { if (t < s) red[t] += red[t + s]; __syncthreads(); }
    float dsum = red[0];
    __syncthreads();
    budget = fmaxf(budget - dsum, 0.f);
    rest = nr;
  }
  int K = (int)rest + 1;
  Kall[win * MQ + t] = K > 1024 ? 1024 : K;
}

// ---------------- graph: cosine-sim + stable top-K keep mask (R11 structure) ----------------
__global__ __launch_bounds__(512, 4) void k_graph(const float* __restrict__ xn,
                                                  const int* __restrict__ Kall,
                                                  unsigned* __restrict__ graph) {
  constexpr int QPB = 8;
  constexpr int RSTR = 1056;                         // row stride: 1024 vals + 32 pad
  __shared__ __align__(16) unsigned smem[QPB * RSTR];// 33KB: values, then hist alias
  int win = blockIdx.x >> 5;
  int qg  = blockIdx.x & 31;
  int wh = win / NHW, ww = win % NHW;
  int t = threadIdx.x;
  // block-uniform query base pointers (scalar)
  const float4* qb[QPB];
#pragma unroll
  for (int q = 0; q < QPB; ++q) {
    int mq = qg * QPB + q;
    int pixq = (wh * WSZ + (mq >> 4)) * WIMG + ww * WSZ + (mq & 15);
    qb[q] = (const float4*)(xn + pixq * CH);
  }
#pragma unroll 1
  for (int kk = 0; kk < 2; ++kk) {
    int j = kk * 512 + t;
    int k0 = j >> 5, k1 = j & 31;
    int py = wh * WSZ - PADS + k0, px = ww * WSZ - PADS + k1;
    bool inb = (py >= 0) && (py < HIMG) && (px >= 0) && (px < WIMG);
    f32x2 acc2[QPB];
#pragma unroll
    for (int q = 0; q < QPB; ++q) acc2[q] = (f32x2){0.f, 0.f};
    if (inb) {
      const float4* s4 = (const float4*)(xn + (py * WIMG + px) * CH);
#pragma unroll 1
      for (int half = 0; half < 2; ++half) {
        union { float4 v4[4]; f32x2 v2[8]; } Y;
#pragma unroll
        for (int r = 0; r < 4; ++r) Y.v4[r] = s4[half * 4 + r];
#pragma unroll
        for (int c4 = 0; c4 < 4; ++c4) {
          f32x2 y0 = Y.v2[2 * c4], y1 = Y.v2[2 * c4 + 1];
#pragma unroll
          for (int q = 0; q < QPB; ++q) {
            float4 qv = qb[q][half * 4 + c4];        // uniform -> s_load
            f32x2 qa = {qv.x, qv.y}, qb2 = {qv.z, qv.w};
            acc2[q] = pkfma(qa, y0, acc2[q]);
            acc2[q] = pkfma(qb2, y1, acc2[q]);
          }
        }
      }
    }
#pragma unroll
    for (int q = 0; q < QPB; ++q) smem[q * RSTR + j] = sortable(acc2[q].x + acc2[q].y);
  }
  __syncthreads();
  // ---- select: wave w owns query m = qg*QPB + w; row w is wave-exclusive ----
  int w = t >> 6, l = t & 63;
  unsigned* row = &smem[w * RSTR];
  int m = qg * QPB + w;
  int K = Kall[win * MQ + m];
  unsigned row32 = (unsigned)(win * MQ + m) * 32u;
  if (K >= NKEY) {                       // keep everything
    if (l < 32) graph[row32 + l] = ~0u;
    return;
  }
  unsigned v[16];
#pragma unroll
  for (int k = 0; k < 16; ++k) v[k] = row[k * 64 + l];
  __asm__ volatile("s_waitcnt lgkmcnt(0)" ::: "memory");  // row reads done before overwrite
  unsigned pref = 0;
  int remK = K;
  int shift = 24;
  unsigned ustar = 0;
  int quota = 0;
  for (int pass = 0; pass < 4; ++pass) {
    uint4 z = make_uint4(0u, 0u, 0u, 0u);
    if (pass == 0) {                     // zero 4 skewed copies (words 0..1055)
#pragma unroll
      for (int c = 0; c < 4; ++c) *(uint4*)&row[c * 256 + l * 4] = z;
      if (l < 8) *(uint4*)&row[1024 + l * 4] = z;
    } else {
      *(uint4*)&row[l * 4] = z;
    }
    __asm__ volatile("s_waitcnt lgkmcnt(0)" ::: "memory");
    int cbase = (l & 3) * 257;           // bank-skewed copy for this lane
#pragma unroll
    for (int k = 0; k < 16; ++k) {
      unsigned u = v[k];
      bool ok = (pass == 0) || ((u >> ((shift + 8) & 31)) == pref);
      if (ok) {
        unsigned bin = (u >> shift) & 255u;
        atomicAdd(&row[(pass == 0 ? cbase : 0) + bin], 1u);
      }
    }
    __asm__ volatile("s_waitcnt lgkmcnt(0)" ::: "memory");
    unsigned c0, c1, c2, c3;
    if (pass == 0) {
      c0 = c1 = c2 = c3 = 0u;
#pragma unroll
      for (int c = 0; c < 4; ++c) {
        c0 += row[c * 257 + l * 4 + 0];
        c1 += row[c * 257 + l * 4 + 1];
        c2 += row[c * 257 + l * 4 + 2];
        c3 += row[c * 257 + l * 4 + 3];
      }
    } else {
      uint4 hv = *(const uint4*)&row[l * 4];
      c0 = hv.x; c1 = hv.y; c2 = hv.z; c3 = hv.w;
    }
    unsigned s3 = c3, s2 = c3 + c2, s1 = s2 + c1, s0 = s1 + c0;
    unsigned I = s0;
#pragma unroll
    for (int off = 1; off < 64; off <<= 1) {
      unsigned tv = __shfl_down(I, off);
      if (l + off < 64) I += tv;
    }
    unsigned E = I - s0;   // counts in lanes above (higher bins)
    int bin = -1, newrem = 0;
    bool early = false;
    {
      int sb, sb1;
      sb = (int)(s3 + E); sb1 = (int)E;
      if (sb >= remK && sb1 < remK) { bin = l * 4 + 3; newrem = remK - sb1; early = (sb == remK); }
      sb = (int)(s2 + E); sb1 = (int)(s3 + E);
      if (sb >= remK && sb1 < remK) { bin = l * 4 + 2; newrem = remK - sb1; early = (sb == remK); }
      sb = (int)(s1 + E); sb1 = (int)(s2 + E);
      if (sb >= remK && sb1 < remK) { bin = l * 4 + 1; newrem = remK - sb1; early = (sb == remK); }
      sb = (int)(s0 + E); sb1 = (int)(s1 + E);
      if (sb >= remK && sb1 < remK) { bin = l * 4 + 0; newrem = remK - sb1; early = (sb == remK); }
    }
    unsigned long long bal = __ballot(bin >= 0);
    int src = __ffsll((long long)bal) - 1;
    int pk = newrem | (bin << 11) | (early ? (1 << 20) : 0);
    pk = __shfl(pk, src);
    pref = (pref << 8) | (unsigned)((pk >> 11) & 255);
    remK = pk & 0x7FF;
    if (((pk >> 20) & 1) || pass == 3) { ustar = pref << shift; quota = remK; break; }
    // exact-resolve: if all candidates matching the new prefix are equal, done
    unsigned mn = ~0u, mx = 0u;
#pragma unroll
    for (int k = 0; k < 16; ++k) {
      if ((v[k] >> shift) == pref) {
        mn = v[k] < mn ? v[k] : mn;
        mx = v[k] > mx ? v[k] : mx;
      }
    }
#pragma unroll
    for (int off = 1; off < 64; off <<= 1) {
      unsigned mno = (unsigned)__shfl_xor((int)mn, off);
      unsigned mxo = (unsigned)__shfl_xor((int)mx, off);
      mn = mno < mn ? mno : mn;
      mx = mxo > mx ? mxo : mx;
    }
    if (mn == mx) { ustar = mn; quota = remK; break; }
    shift -= 8;
  }
  // ---- keep mask: stable (ascending key index) among ties; coalesced write ----
  int running = 0;
  unsigned saved = 0;
#pragma unroll
  for (int k = 0; k < 16; ++k) {
    unsigned u = v[k];
    bool eq = (u == ustar);
    unsigned long long beq = __ballot(eq);
    int before = running + (int)__popcll(beq & ((1ull << l) - 1ull));
    bool keep = (u > ustar) || (eq && before < quota);
    running += (int)__popcll(beq);
    unsigned long long kb = __ballot(keep);
    if ((l >> 1) == k) saved = (l & 1) ? (unsigned)(kb >> 32) : (unsigned)kb;
  }
  if (l < 32) graph[row32 + l] = saved;
}

// ---------------- attention: block = (win, head, q-quarter); trig from table ----------------
#define MERGEA(MSK) {                                              \
  float mo = __shfl_xor(mrun, MSK);                                \
  float lo = __shfl_xor(lrun, MSK);                                \
  float b0 = __shfl_xor(__builtin_bit_cast(float, a0), MSK);       \
  float b1 = __shfl_xor(__builtin_bit_cast(float, a1), MSK);       \
  float b2 = __shfl_xor(__builtin_bit_cast(float, a2), MSK);       \
  float b3 = __shfl_xor(__builtin_bit_cast(float, a3), MSK);       \
  float mn = fmaxf(mrun, mo);                                      \
  float c1 = __expf(mrun - mn), c2 = __expf(mo - mn);              \
  lrun = lrun * c1 + lo * c2;                                      \
  h2 c1h = mkh2(c1), c2h = mkh2(c2);                               \
  a0 = a0 * c1h + __builtin_bit_cast(h2, b0) * c2h;                \
  a1 = a1 * c1h + __builtin_bit_cast(h2, b1) * c2h;                \
  a2 = a2 * c1h + __builtin_bit_cast(h2, b2) * c2h;                \
  a3 = a3 * c1h + __builtin_bit_cast(h2, b3) * c2h;                \
  mrun = mn; }

__global__ __launch_bounds__(256, 4) void k_attn(const float* __restrict__ qn,
                                                 const float* __restrict__ y_px,
                                                 const float* __restrict__ trigtab,
                                                 const unsigned* __restrict__ graph,
                                                 float* __restrict__ att) {
  __shared__ uint4 knp[NKEY];   // 16KB: 8 x fp16 normalized rope'd k
  __shared__ uint4 fvp[NKEY];   // 16KB: 8 x fp16 v
  int bid = blockIdx.x;
  int qq  = bid & 3;
  int h   = (bid >> 2) & 3;
  int win = bid >> 4;
  int wh = win / NHW, ww = win % NHW;
  int t = threadIdx.x;
  const float4* tg = (const float4*)trigtab;
#pragma unroll
  for (int r = 0; r < 4; ++r) {
    int j = r * 256 + t;
    int k0 = j >> 5, k1 = j & 31;
    int py = wh * WSZ - PADS + k0, px = ww * WSZ - PADS + k1;
    bool inb = (py >= 0) && (py < HIMG) && (px >= 0) && (px < WIMG);
    float kv[8], fw[8];
    if (inb) {
      const float* src = y_px + (py * WIMG + px) * 64 + h * HDIM;
      const float4* a4 = (const float4*)src;
      const float4* b4 = (const float4*)(src + 32);
      float4 a0 = a4[0], a1 = a4[1], b0 = b4[0], b1 = b4[1];
      kv[0]=a0.x; kv[1]=a0.y; kv[2]=a0.z; kv[3]=a0.w;
      kv[4]=a1.x; kv[5]=a1.y; kv[6]=a1.z; kv[7]=a1.w;
      fw[0]=b0.x; fw[1]=b0.y; fw[2]=b0.z; fw[3]=b0.w;
      fw[4]=b1.x; fw[5]=b1.y; fw[6]=b1.z; fw[7]=b1.w;
    } else {
#pragma unroll
      for (int d = 0; d < 8; ++d) { kv[d] = 0.f; fw[d] = 0.f; }
    }
    float4 T0 = tg[j * 2], T1 = tg[j * 2 + 1];   // (c0,s0,c1,s1), (c2,s2,c3,s3)
    float ro[8];
    ro[0] = kv[0] * T0.x - kv[1] * T0.y;
    ro[1] = kv[1] * T0.x + kv[0] * T0.y;
    ro[2] = kv[2] * T0.z - kv[3] * T0.w;
    ro[3] = kv[3] * T0.z + kv[2] * T0.w;
    ro[4] = kv[4] * T1.x - kv[5] * T1.y;
    ro[5] = kv[5] * T1.x + kv[4] * T1.y;
    ro[6] = kv[6] * T1.z - kv[7] * T1.w;
    ro[7] = kv[7] * T1.z + kv[6] * T1.w;
    float ss = 0.f;
#pragma unroll
    for (int d = 0; d < 8; ++d) ss += ro[d] * ro[d];
    float iv = 1.f / fmaxf(sqrtf(ss), 1e-12f);
    union { uint4 u; h2 v[4]; } ku, fu;
#pragma unroll
    for (int p = 0; p < 4; ++p) {
      h2 kk = { (half_t)(ro[2*p] * iv), (half_t)(ro[2*p+1] * iv) };
      h2 ff = { (half_t)fw[2*p], (half_t)fw[2*p+1] };
      ku.v[p] = kk; fu.v[p] = ff;
    }
    knp[j] = ku.u;
    fvp[j] = fu.u;
  }
  __syncthreads();
  int s = t & 3, ql = t >> 2;
  int m = qq * 64 + ql;
  const float* qp = qn + (win * MQ + m) * CH + h * HDIM;
  h2 q0 = { (half_t)qp[0], (half_t)qp[1] };
  h2 q1 = { (half_t)qp[2], (half_t)qp[3] };
  h2 q2 = { (half_t)qp[4], (half_t)qp[5] };
  h2 q3 = { (half_t)qp[6], (half_t)qp[7] };
  const unsigned* gr = graph + (size_t)(win * MQ + m) * 32 + s * 8;
  float mrun = -1e30f, lrun = 0.f;
  h2 a0 = {0,0}, a1 = {0,0}, a2 = {0,0}, a3 = {0,0};
  int jbase = s * 256;
  for (int w8 = 0; w8 < 8; ++w8) {
    unsigned bits = gr[w8];
    while (bits) {
      int bb = __ffs(bits) - 1;
      bits &= bits - 1;
      int j = jbase + w8 * 32 + bb;
      uint4 kv = knp[j];
      float sd = __builtin_amdgcn_fdot2(q0, __builtin_bit_cast(h2, kv.x), 0.f, false);
      sd = __builtin_amdgcn_fdot2(q1, __builtin_bit_cast(h2, kv.y), sd, false);
      sd = __builtin_amdgcn_fdot2(q2, __builtin_bit_cast(h2, kv.z), sd, false);
      sd = __builtin_amdgcn_fdot2(q3, __builtin_bit_cast(h2, kv.w), sd, false);
      sd *= SCL;
      uint4 fw = fvp[j];
      if (sd <= mrun) {
        float pw = __expf(sd - mrun);
        lrun += pw;
        h2 ph = mkh2(pw);
        a0 += __builtin_bit_cast(h2, fw.x) * ph;
        a1 += __builtin_bit_cast(h2, fw.y) * ph;
        a2 += __builtin_bit_cast(h2, fw.z) * ph;
        a3 += __builtin_bit_cast(h2, fw.w) * ph;
      } else {
        float corr = __expf(mrun - sd);
        lrun = lrun * corr + 1.f;
        h2 ch = mkh2(corr);
        a0 = a0 * ch + __builtin_bit_cast(h2, fw.x);
        a1 = a1 * ch + __builtin_bit_cast(h2, fw.y);
        a2 = a2 * ch + __builtin_bit_cast(h2, fw.z);
        a3 = a3 * ch + __builtin_bit_cast(h2, fw.w);
        mrun = sd;
      }
    }
  }
  MERGEA(1);
  MERGEA(2);
  float invl = 1.f / lrun;
  h2 sel;
  if (s == 0) sel = a0; else if (s == 1) sel = a1; else if (s == 2) sel = a2; else sel = a3;
  float* op = att + (size_t)(win * MQ + m) * CH + h * HDIM + s * 2;
  op[0] = (float)sel.x * invl;
  op[1] = (float)sel.y * invl;
}

// ---------------- out @ Wp^T + bp -> image layout; 64 px x 4 oc-quarters ----------------
__global__ __launch_bounds__(256) void k_img(const float* __restrict__ att,
                                             const float* __restrict__ Wp,
                                             const float* __restrict__ bp,
                                             float* __restrict__ img) {
  __shared__ __align__(16) float w[CH * CH];
  __shared__ float b[CH];
  int t = threadIdx.x;
  for (int i = t; i < CH * CH; i += 256) w[i] = Wp[i];
  if (t < CH) b[t] = bp[t];
  __syncthreads();
  int g = t >> 6, lane = t & 63;
  int gq = blockIdx.x * 64 + lane;
  int win = gq >> 8, m = gq & 255;
  int wh = win / NHW, ww = win % NHW;
  int pix = (wh * WSZ + (m >> 4)) * WIMG + ww * WSZ + (m & 15);
  union { float4 v4[8]; float f[CH]; } a;
  const float4* ap = (const float4*)(att + (size_t)gq * CH);
#pragma unroll
  for (int r = 0; r < 8; ++r) a.v4[r] = ap[r];
#pragma unroll
  for (int k = 0; k < 8; ++k) {
    int oc = g * 8 + k;
    float acc = b[oc];
    const float4* wv = (const float4*)&w[oc * CH];
#pragma unroll
    for (int c4 = 0; c4 < 8; ++c4) {
      float4 wq = wv[c4];
      acc += wq.x * a.f[4*c4] + wq.y * a.f[4*c4+1] + wq.z * a.f[4*c4+2] + wq.w * a.f[4*c4+3];
    }
    img[oc * NPIX + pix] = acc;
  }
}

// ---------------- 3x3 conv + channel LayerNorm + residual ----------------
#define CACC(W, I0) { o[I0] += (W).x * xv; o[I0+1] += (W).y * xv; o[I0+2] += (W).z * xv; o[I0+3] += (W).w * xv; }

__global__ __launch_bounds__(256) void k_convln(const float* __restrict__ img,
                                                const float* __restrict__ Wc,
                                                const float* __restrict__ bc,
                                                const float* __restrict__ gamma,
                                                const float* __restrict__ beta,
                                                float* __restrict__ out) {
  __shared__ float tile[CH][10][18];              // 23.0 KB
  __shared__ __align__(16) float wt[288][CH];     // 36.9 KB, transposed weights
  __shared__ float red[128][2][2];                // 2 KB
  int t = threadIdx.x;
  int by = (blockIdx.x / 12) * 8, bx = (blockIdx.x % 12) * 16;
  for (int i = t; i < 288 * CH; i += 256) {
    int oc = i & 31, icd = i >> 5;
    wt[icd][oc] = Wc[oc * 288 + icd];
  }
  for (int i = t; i < CH * 10 * 18; i += 256) {
    int c = i / 180; int rr = (i % 180) / 18; int cl = i % 18;
    int gy = by + rr - 1, gx = bx + cl - 1;
    tile[c][rr][cl] = (gy >= 0 && gy < HIMG && gx >= 0 && gx < WIMG)
                          ? img[c * NPIX + gy * WIMG + gx] : 0.f;
  }
  __syncthreads();
  int g = __builtin_amdgcn_readfirstlane((t >> 7) & 1);   // wave-uniform oc half
  int p = t & 127;
  int r = p >> 4, c = p & 15;
  int ocb = g * 16;
  float o[16];
#pragma unroll
  for (int k = 0; k < 16; ++k) o[k] = bc[ocb + k];
  for (int ic = 0; ic < CH; ++ic) {
#pragma unroll
    for (int dy = 0; dy < 3; ++dy) {
#pragma unroll
      for (int dx = 0; dx < 3; ++dx) {
        float xv = tile[ic][r + dy][c + dx];
        const float4* wv = (const float4*)&wt[ic * 9 + dy * 3 + dx][ocb];
        float4 w0 = wv[0], w1 = wv[1], w2 = wv[2], w3 = wv[3];
        CACC(w0, 0); CACC(w1, 4); CACC(w2, 8); CACC(w3, 12);
      }
    }
  }
  float s1 = 0.f, s2 = 0.f;
#pragma unroll
  for (int k = 0; k < 16; ++k) { s1 += o[k]; s2 += o[k] * o[k]; }
  red[p][g][0] = s1; red[p][g][1] = s2;
  __syncthreads();
  float t1 = red[p][g ^ 1][0], t2 = red[p][g ^ 1][1];
  float mu = (s1 + t1) * (1.f / 32.f);
  float ex2 = (s2 + t2) * (1.f / 32.f);
  float var = ex2 - mu * mu;
  float inv = 1.f / sqrtf(var + 1e-5f);
  int pix = (by + r) * WIMG + bx + c;
#pragma unroll
  for (int k = 0; k < 16; ++k) {
    int oc = ocb + k;
    out[oc * NPIX + pix] = tile[oc][r + 1][c + 1] + (o[k] - mu) * inv * gamma[oc] + beta[oc];
  }
}

}  // namespace

extern "C" void kernel_launch(void* const* d_in, const int* in_sizes, int n_in,
                              void* d_out, int out_size, void* d_ws, size_t ws_size,
                              hipStream_t stream) {
  const float* x     = (const float*)d_in[0];
  const float* Wg    = (const float*)d_in[1];
  const float* bg    = (const float*)d_in[2];
  const float* Ws    = (const float*)d_in[3];
  const float* bs    = (const float*)d_in[4];
  const float* Wp    = (const float*)d_in[5];
  const float* bp    = (const float*)d_in[6];
  const float* Wc    = (const float*)d_in[7];
  const float* bc    = (const float*)d_in[8];
  const float* gamma = (const float*)d_in[9];
  const float* beta  = (const float*)d_in[10];
  float* out = (float*)d_out;
  float* ws = (float*)d_ws;

  float* y_px = ws;                             // 2359296 floats
  float* xn   = y_px + 2359296;                 // 1179648
  float* down = xn + 1179648;                   // 294912
  float* trigtab = down + 294912;               // 8192 used (old Xd slot, 36864)
  float* qn   = trigtab + 36864;                // 1179648
  float* att  = qn + 1179648;                   // 1179648
  float* img  = att + 1179648;                  // 1179648
  int* Kall   = (int*)(img + 1179648);          // 36864
  unsigned* graph = (unsigned*)(Kall + 36864);  // 1179648
  if (ws_size < (size_t)8626176 * 4) return;

  k_prep<<<NPIX / 16, 256, 0, stream>>>(x, Ws, bs, Wg, bg, y_px, xn, qn, trigtab);
  k_down<<<(CH * 96 * 96) / 256, 256, 0, stream>>>(x, down);
  k_updalloc<<<NWIN, 256, 0, stream>>>(x, down, Kall);
  k_graph<<<NWIN * 32, 512, 0, stream>>>(xn, Kall, graph);
  k_attn<<<NWIN * NHEAD * 4, 256, 0, stream>>>(qn, y_px, trigtab, graph, att);
  k_img<<<NPIX / 64, 256, 0, stream>>>(att, Wp, bp, img);
  k_convln<<<288, 256, 0, stream>>>(img, Wc, bc, gamma, beta, out);
}